// Round 8
// baseline (94.434 us; speedup 1.0000x reference)
//
#include <hip/hip_runtime.h>
#include <math.h>

#define N_NODES 10000
#define DEG1 33          // DEG + self-loop
#define D_EMB 128
#define F_IN 128
#define BATCH 2

typedef short s8v  __attribute__((ext_vector_type(8)));
typedef float f4v  __attribute__((ext_vector_type(4)));

// fp32 -> bf16 round-to-nearest-even (no NaN special-case; inputs are normal)
static __device__ __forceinline__ unsigned short f2bf(float f) {
    unsigned int x = __float_as_uint(f);
    unsigned int r = (x + 0x7fffu + ((x >> 16) & 1u)) >> 16;
    return (unsigned short)r;
}
static __device__ __forceinline__ float bf_lo(unsigned int u) { return __uint_as_float(u << 16); }
static __device__ __forceinline__ float bf_hi(unsigned int u) { return __uint_as_float(u & 0xffff0000u); }
static __device__ __forceinline__ float rdlane_f(float v, int l) {
    return __uint_as_float((unsigned int)__builtin_amdgcn_readlane((int)__float_as_uint(v), l));
}

// ---------------------------------------------------------------------------
// Kernel 0 (prep): pack W (128x128 fp32) into bf16 B-fragments for
// mfma_f32_16x16x32_bf16:  B[k = s*32 + (l>>4)*8 + j][n = c*16 + (l&15)]
// layout wtf[((c*4+s)*64 + l)*8 + j]  (16B/lane -> coalesced dwordx4 loads).
// ---------------------------------------------------------------------------
__global__ __launch_bounds__(256) void gat_prep_kernel(
    const float* __restrict__ W, unsigned short* __restrict__ wtf)
{
    const int c = blockIdx.x;
    const int t = threadIdx.x;
    __shared__ float xs[128 * 16];   // W[:, c*16 .. c*16+16)
    #pragma unroll
    for (int r = 0; r < 8; ++r) {
        const int k = r * 16 + (t >> 4);
        const int n = t & 15;
        xs[k * 16 + n] = W[k * 128 + c * 16 + n];
    }
    __syncthreads();
    const int s = t >> 6;    // k-step 0..3
    const int l = t & 63;    // lane
    s8v frag;
    #pragma unroll
    for (int j = 0; j < 8; ++j) {
        const int k = s * 32 + (l >> 4) * 8 + j;
        frag[j] = (short)f2bf(xs[k * 16 + (l & 15)]);
    }
    *(s8v*)&wtf[(((size_t)c * 4 + s) * 64 + l) * 8] = frag;
}

// ---------------------------------------------------------------------------
// Kernel 1: h = X @ W via bf16 MFMA (wave = 16 rows x 128 cols, no LDS in
// main loop). s = h.a_src, d = h.a_dst from fp32 accumulators.
// h stored bf16 in TWO half-dim tables (dims 0-63 -> hbA, 64-127 -> hbB),
// each batch-interleaved [(n*2+b)*64 + col]: 2.56 MB each < 4 MiB per-XCD
// L2, so each agg pass's gather is L2-resident.
// ---------------------------------------------------------------------------
__global__ __launch_bounds__(256) void gat_h_kernel(
    const float* __restrict__ X, const unsigned short* __restrict__ wtf,
    const float* __restrict__ Wattn,
    unsigned short* __restrict__ hbA, unsigned short* __restrict__ hbB,
    float* __restrict__ s_arr, float* __restrict__ d_arr)
{
    const int w = blockIdx.x * 4 + (threadIdx.x >> 6);   // global wave id
    if (w >= (BATCH * N_NODES) / 16) return;             // 1250 waves exactly
    const int lane = threadIdx.x & 63;
    const int quad = lane >> 4;
    const int mrow = lane & 15;
    const int row0 = w * 16;

    f4v acc[8];
    #pragma unroll
    for (int c = 0; c < 8; ++c) acc[c] = (f4v){0.f, 0.f, 0.f, 0.f};

    const float* xrow = X + (size_t)(row0 + mrow) * F_IN;
    #pragma unroll
    for (int s = 0; s < 4; ++s) {
        const int k0 = s * 32 + quad * 8;
        const float4 xa = *(const float4*)&xrow[k0];
        const float4 xbv = *(const float4*)&xrow[k0 + 4];
        s8v a;
        a[0] = (short)f2bf(xa.x);  a[1] = (short)f2bf(xa.y);
        a[2] = (short)f2bf(xa.z);  a[3] = (short)f2bf(xa.w);
        a[4] = (short)f2bf(xbv.x); a[5] = (short)f2bf(xbv.y);
        a[6] = (short)f2bf(xbv.z); a[7] = (short)f2bf(xbv.w);
        #pragma unroll
        for (int c = 0; c < 8; ++c) {
            const s8v b = *(const s8v*)&wtf[(((size_t)c * 4 + s) * 64 + lane) * 8];
            acc[c] = __builtin_amdgcn_mfma_f32_16x16x32_bf16(a, b, acc[c], 0, 0, 0);
        }
    }

    // ---- store h (bf16) into the two half-dim tables ----
    const int b = (row0 >= N_NODES) ? 1 : 0;
    #pragma unroll
    for (int r = 0; r < 4; ++r) {
        const int R = row0 + quad * 4 + r;
        const int n = R - b * N_NODES;
        const size_t base = ((size_t)n * 2 + b) * 64 + mrow;
        #pragma unroll
        for (int c = 0; c < 8; ++c) {
            unsigned short* tab = (c < 4) ? hbA : hbB;
            tab[base + (c & 3) * 16] = f2bf(acc[c][r]);
        }
    }

    // ---- s/d dots: reduce across the 16 lanes (mrow) of each quad ----
    float as[8], ad[8];
    #pragma unroll
    for (int c = 0; c < 8; ++c) {
        as[c] = Wattn[c * 16 + mrow];
        ad[c] = Wattn[D_EMB + c * 16 + mrow];
    }
    #pragma unroll
    for (int r = 0; r < 4; ++r) {
        float sv = 0.f, dv = 0.f;
        #pragma unroll
        for (int c = 0; c < 8; ++c) {
            sv = fmaf(acc[c][r], as[c], sv);
            dv = fmaf(acc[c][r], ad[c], dv);
        }
        #pragma unroll
        for (int off = 1; off < 16; off <<= 1) {
            sv += __shfl_xor(sv, off, 16);
            dv += __shfl_xor(dv, off, 16);
        }
        if (mrow == 0) {
            const int R = row0 + quad * 4 + r;
            s_arr[R] = sv;
            d_arr[R] = dv;
        }
    }
}

// ---------------------------------------------------------------------------
// Kernel 2 (run twice, half=0 then half=1): edge phase over ONE half-dim
// table (2.56 MB -> L2-resident). Wave = node, 4 independent waves per
// block, no barriers/LDS. Scores recomputed per pass (cheap VALU); denom
// from batch 0 only (ref semantics), inv folded into scores. Per-edge
// dst/weights via readlane -> SGPR; gather = one saddr dword per edge
// covering both batches' 128B half-rows (256B/wave-edge).
// ---------------------------------------------------------------------------
__global__ __launch_bounds__(256) void gat_agg_half_kernel(
    const unsigned int* __restrict__ tab,   // bf16x2 [(n*2+b)*32 + dl]
    const float* __restrict__ s_arr, const float* __restrict__ d_arr,
    const int* __restrict__ edges, float* __restrict__ out, const int half)
{
    const int i = blockIdx.x * 4 + (threadIdx.x >> 6);   // node
    const int lane = threadIdx.x & 63;

    int dstv = 0; float sc0 = 0.f, sc1 = 0.f;
    if (lane < DEG1) {
        dstv = edges[((size_t)i * DEG1 + lane) * 2 + 1];
        float x0 = s_arr[i] + d_arr[dstv];
        float x1 = s_arr[N_NODES + i] + d_arr[N_NODES + dstv];
        x0 = (x0 >= 0.f) ? x0 : 0.2f * x0;            // leaky_relu(0.2)
        x1 = (x1 >= 0.f) ? x1 : 0.2f * x1;
        sc0 = __expf(fminf(fmaxf(x0, -2.f), 2.f));
        sc1 = __expf(fminf(fmaxf(x1, -2.f), 2.f));
    }
    float dsum = sc0;              // denom from batch 0 only (ref semantics)
    #pragma unroll
    for (int off = 1; off < 64; off <<= 1) dsum += __shfl_xor(dsum, off, 64);
    const float inv = 1.f / dsum;
    sc0 *= inv;                    // fold inv_denom into both batches' scores
    sc1 *= inv;

    // lanes 0..31: batch-0 dims 2*dl..2*dl+1 of this half; lanes 32..63: batch-1
    const int b  = lane >> 5;
    const int dl = lane & 31;
    float2 acc = make_float2(0.f, 0.f);
    #pragma unroll
    for (int j = 0; j < DEG1; ++j) {
        const int   dd = __builtin_amdgcn_readlane(dstv, j);   // SGPR
        const float w0 = rdlane_f(sc0, j);                     // SGPR
        const float w1 = rdlane_f(sc1, j);                     // SGPR
        const float wgt = (lane < 32) ? w0 : w1;
        const unsigned int u = tab[(((size_t)dd * 2 + b) << 5) + dl];  // saddr + lane*4
        acc.x = fmaf(wgt, bf_lo(u), acc.x);
        acc.y = fmaf(wgt, bf_hi(u), acc.y);
    }
    // combine batches: partner lane (lane ^ 32) holds the other batch's
    // partial for the SAME dims
    float2 o;
    o.x = acc.x + __shfl_xor(acc.x, 32, 64);
    o.y = acc.y + __shfl_xor(acc.y, 32, 64);

    // lane writes batch b's copy of dims half*64 + 2*dl .. +1 (copies identical)
    float2* out2 = (float2*)out;
    out2[((size_t)b * N_NODES + i) * (D_EMB / 2) + half * 32 + dl] = o;
}

extern "C" void kernel_launch(void* const* d_in, const int* in_sizes, int n_in,
                              void* d_out, int out_size, void* d_ws, size_t ws_size,
                              hipStream_t stream) {
    const float* X     = (const float*)d_in[0];   // (2, 10000, 128) fp32
    const float* W     = (const float*)d_in[1];   // (128, 128) fp32
    const float* Wattn = (const float*)d_in[2];   // (256, 1) fp32
    const int*   edges = (const int*)d_in[3];     // (330000, 2) int32
    float* out = (float*)d_out;                   // (2, 10000, 128) fp32

    unsigned short* wtf = (unsigned short*)d_ws;                 // 16384 bf16 = 32KB
    unsigned short* hbA = wtf + 16384;                           // 2*10000*64 bf16 = 2.56MB
    unsigned short* hbB = hbA + (size_t)BATCH * N_NODES * 64;    // 2.56MB
    float* s_arr = (float*)(hbB + (size_t)BATCH * N_NODES * 64);
    float* d_arr = s_arr + BATCH * N_NODES;

    gat_prep_kernel<<<8, 256, 0, stream>>>(W, wtf);
    gat_h_kernel<<<313, 256, 0, stream>>>(X, wtf, Wattn, hbA, hbB, s_arr, d_arr);
    gat_agg_half_kernel<<<N_NODES / 4, 256, 0, stream>>>(
        (const unsigned int*)hbA, s_arr, d_arr, edges, out, 0);
    gat_agg_half_kernel<<<N_NODES / 4, 256, 0, stream>>>(
        (const unsigned int*)hbB, s_arr, d_arr, edges, out, 1);
}

// Round 9
// 90.884 us; speedup vs baseline: 1.0391x; 1.0391x over previous
//
#include <hip/hip_runtime.h>
#include <math.h>

#define N_NODES 10000
#define DEG1 33          // DEG + self-loop
#define D_EMB 128
#define F_IN 128
#define BATCH 2

typedef short s8v  __attribute__((ext_vector_type(8)));
typedef float f4v  __attribute__((ext_vector_type(4)));

// fp32 -> bf16 round-to-nearest-even (no NaN special-case; inputs are normal)
static __device__ __forceinline__ unsigned short f2bf(float f) {
    unsigned int x = __float_as_uint(f);
    unsigned int r = (x + 0x7fffu + ((x >> 16) & 1u)) >> 16;
    return (unsigned short)r;
}
static __device__ __forceinline__ float bf_lo(unsigned int u) { return __uint_as_float(u << 16); }
static __device__ __forceinline__ float bf_hi(unsigned int u) { return __uint_as_float(u & 0xffff0000u); }
static __device__ __forceinline__ float rdlane_f(float v, int l) {
    return __uint_as_float((unsigned int)__builtin_amdgcn_readlane((int)__float_as_uint(v), l));
}

// ---------------------------------------------------------------------------
// Kernel 0 (prep): pack W (128x128 fp32) into bf16 B-fragments for
// mfma_f32_16x16x32_bf16:  B[k = s*32 + (l>>4)*8 + j][n = c*16 + (l&15)]
// layout wtf[((c*4+s)*64 + l)*8 + j]  (16B/lane -> coalesced dwordx4 loads).
// ---------------------------------------------------------------------------
__global__ __launch_bounds__(256) void gat_prep_kernel(
    const float* __restrict__ W, unsigned short* __restrict__ wtf)
{
    const int c = blockIdx.x;
    const int t = threadIdx.x;
    __shared__ float xs[128 * 16];   // W[:, c*16 .. c*16+16)
    #pragma unroll
    for (int r = 0; r < 8; ++r) {
        const int k = r * 16 + (t >> 4);
        const int n = t & 15;
        xs[k * 16 + n] = W[k * 128 + c * 16 + n];
    }
    __syncthreads();
    const int s = t >> 6;    // k-step 0..3
    const int l = t & 63;    // lane
    s8v frag;
    #pragma unroll
    for (int j = 0; j < 8; ++j) {
        const int k = s * 32 + (l >> 4) * 8 + j;
        frag[j] = (short)f2bf(xs[k * 16 + (l & 15)]);
    }
    *(s8v*)&wtf[(((size_t)c * 4 + s) * 64 + l) * 8] = frag;
}

// ---------------------------------------------------------------------------
// Kernel 1: h = X @ W via bf16 MFMA. Wave = 16 rows x 64 cols (col-half):
// 2500 waves (2x the 16x128 version) for latency hiding; the two col-half
// waves of a row-group share X rows (L1 reuse). Partial s/d dots combined
// via tiny LDS + one barrier. h stored bf16 batch-interleaved
// hb[(n*2+b)*128 + col] with NONTEMPORAL stores so the table is not left
// dirty in the writer XCD's L2 (agg reads are cross-XCD).
// ---------------------------------------------------------------------------
__global__ __launch_bounds__(256) void gat_h_kernel(
    const float* __restrict__ X, const unsigned short* __restrict__ wtf,
    const float* __restrict__ Wattn,
    unsigned short* __restrict__ hb, float* __restrict__ s_arr, float* __restrict__ d_arr)
{
    __shared__ float lds_sd[2][2][2][16];   // [rowgroup][colhalf][s|d][row]
    const int wave = threadIdx.x >> 6;
    const int lane = threadIdx.x & 63;
    const int quad = lane >> 4;
    const int mrow = lane & 15;
    const int rg   = wave >> 1;              // row-group within block (0,1)
    const int half = wave & 1;               // col half (0,1)
    const int row0 = (blockIdx.x * 2 + rg) * 16;

    f4v acc[4];
    #pragma unroll
    for (int cc = 0; cc < 4; ++cc) acc[cc] = (f4v){0.f, 0.f, 0.f, 0.f};

    const float* xrow = X + (size_t)(row0 + mrow) * F_IN;
    #pragma unroll
    for (int s = 0; s < 4; ++s) {
        const int k0 = s * 32 + quad * 8;
        const float4 xa = *(const float4*)&xrow[k0];
        const float4 xbv = *(const float4*)&xrow[k0 + 4];
        s8v a;
        a[0] = (short)f2bf(xa.x);  a[1] = (short)f2bf(xa.y);
        a[2] = (short)f2bf(xa.z);  a[3] = (short)f2bf(xa.w);
        a[4] = (short)f2bf(xbv.x); a[5] = (short)f2bf(xbv.y);
        a[6] = (short)f2bf(xbv.z); a[7] = (short)f2bf(xbv.w);
        #pragma unroll
        for (int cc = 0; cc < 4; ++cc) {
            const int c = half * 4 + cc;
            const s8v b = *(const s8v*)&wtf[(((size_t)c * 4 + s) * 64 + lane) * 8];
            acc[cc] = __builtin_amdgcn_mfma_f32_16x16x32_bf16(a, b, acc[cc], 0, 0, 0);
        }
    }

    // ---- store h (bf16, interleaved (n,b)), NONTEMPORAL ----
    const int b = (row0 >= N_NODES) ? 1 : 0;
    #pragma unroll
    for (int r = 0; r < 4; ++r) {
        const int R = row0 + quad * 4 + r;
        const int n = R - b * N_NODES;
        unsigned short* dst = &hb[((size_t)n * 2 + b) * D_EMB + half * 64 + mrow];
        #pragma unroll
        for (int cc = 0; cc < 4; ++cc)
            __builtin_nontemporal_store(f2bf(acc[cc][r]), &dst[cc * 16]);
    }

    // ---- partial s/d dots over this wave's 64 cols ----
    float as[4], ad[4];
    #pragma unroll
    for (int cc = 0; cc < 4; ++cc) {
        as[cc] = Wattn[(half * 4 + cc) * 16 + mrow];
        ad[cc] = Wattn[D_EMB + (half * 4 + cc) * 16 + mrow];
    }
    #pragma unroll
    for (int r = 0; r < 4; ++r) {
        float sv = 0.f, dv = 0.f;
        #pragma unroll
        for (int cc = 0; cc < 4; ++cc) {
            sv = fmaf(acc[cc][r], as[cc], sv);
            dv = fmaf(acc[cc][r], ad[cc], dv);
        }
        #pragma unroll
        for (int off = 1; off < 16; off <<= 1) {
            sv += __shfl_xor(sv, off, 16);
            dv += __shfl_xor(dv, off, 16);
        }
        if (mrow == 0) {
            lds_sd[rg][half][0][quad * 4 + r] = sv;
            lds_sd[rg][half][1][quad * 4 + r] = dv;
        }
    }
    __syncthreads();
    const int t = threadIdx.x;
    if (t < 64) {
        const int rg2 = t >> 5, r = (t >> 1) & 15, which = t & 1;
        const float val = lds_sd[rg2][0][which][r] + lds_sd[rg2][1][which][r];
        const int row = (blockIdx.x * 2 + rg2) * 16 + r;
        if (which == 0) s_arr[row] = val; else d_arr[row] = val;
    }
}

// ---------------------------------------------------------------------------
// Kernel 2: edge phase. Wave = node, four independent waves per 256-thread
// block (32 waves/CU), no barriers/LDS. Per-edge dst/weights via readlane ->
// SGPR; gather = one saddr dwordx2 covering both batches' interleaved bf16
// rows (512B/edge). inv_denom (batch-0 denom, ref semantics) folded into
// scores; batches combined via shfl_xor(32). out stores NONTEMPORAL so the
// 10.24 MB of write traffic doesn't evict the h table from the reader L2.
// ---------------------------------------------------------------------------
__global__ __launch_bounds__(256) void gat_agg_kernel(
    const uint2* __restrict__ h2, const float* __restrict__ s_arr,
    const float* __restrict__ d_arr, const int* __restrict__ edges,
    float* __restrict__ out)
{
    const int i = blockIdx.x * 4 + (threadIdx.x >> 6);   // node
    const int lane = threadIdx.x & 63;

    int dstv = 0; float sc0 = 0.f, sc1 = 0.f;
    if (lane < DEG1) {
        dstv = edges[((size_t)i * DEG1 + lane) * 2 + 1];
        float x0 = s_arr[i] + d_arr[dstv];
        float x1 = s_arr[N_NODES + i] + d_arr[N_NODES + dstv];
        x0 = (x0 >= 0.f) ? x0 : 0.2f * x0;            // leaky_relu(0.2)
        x1 = (x1 >= 0.f) ? x1 : 0.2f * x1;
        sc0 = __expf(fminf(fmaxf(x0, -2.f), 2.f));
        sc1 = __expf(fminf(fmaxf(x1, -2.f), 2.f));
    }
    float dsum = sc0;              // denom from batch 0 only (ref semantics)
    #pragma unroll
    for (int off = 1; off < 64; off <<= 1) dsum += __shfl_xor(dsum, off, 64);
    const float inv = 1.f / dsum;
    sc0 *= inv;                    // fold inv_denom into both batches' scores
    sc1 *= inv;

    // lanes 0..31: batch-0 dims 4*lane..4*lane+3; lanes 32..63: batch-1 same
    float4 acc = make_float4(0.f, 0.f, 0.f, 0.f);
    #pragma unroll
    for (int j = 0; j < DEG1; ++j) {
        const int   dd = __builtin_amdgcn_readlane(dstv, j);   // SGPR
        const float w0 = rdlane_f(sc0, j);                     // SGPR
        const float w1 = rdlane_f(sc1, j);                     // SGPR
        const float wgt = (lane < 32) ? w0 : w1;
        const uint2 hv = h2[(size_t)dd * 64 + lane];           // saddr + lane*8
        acc.x = fmaf(wgt, bf_lo(hv.x), acc.x);
        acc.y = fmaf(wgt, bf_hi(hv.x), acc.y);
        acc.z = fmaf(wgt, bf_lo(hv.y), acc.z);
        acc.w = fmaf(wgt, bf_hi(hv.y), acc.w);
    }
    // combine batches: partner lane (lane ^ 32) holds the other batch's
    // partial for the SAME dims
    f4v o;
    o[0] = acc.x + __shfl_xor(acc.x, 32, 64);
    o[1] = acc.y + __shfl_xor(acc.y, 32, 64);
    o[2] = acc.z + __shfl_xor(acc.z, 32, 64);
    o[3] = acc.w + __shfl_xor(acc.w, 32, 64);

    const int b  = lane >> 5;        // which batch's copy this lane writes
    const int dl = lane & 31;        // dim group
    __builtin_nontemporal_store(o, (f4v*)&out[((size_t)b * N_NODES + i) * D_EMB + dl * 4]);
}

extern "C" void kernel_launch(void* const* d_in, const int* in_sizes, int n_in,
                              void* d_out, int out_size, void* d_ws, size_t ws_size,
                              hipStream_t stream) {
    const float* X     = (const float*)d_in[0];   // (2, 10000, 128) fp32
    const float* W     = (const float*)d_in[1];   // (128, 128) fp32
    const float* Wattn = (const float*)d_in[2];   // (256, 1) fp32
    const int*   edges = (const int*)d_in[3];     // (330000, 2) int32
    float* out = (float*)d_out;                   // (2, 10000, 128) fp32

    unsigned short* wtf = (unsigned short*)d_ws;                 // 16384 bf16 = 32KB
    unsigned short* hb  = wtf + 16384;                           // (n,b) interleaved bf16
    float* s_arr = (float*)(hb + (size_t)BATCH * N_NODES * D_EMB);
    float* d_arr = s_arr + BATCH * N_NODES;

    gat_prep_kernel<<<8, 256, 0, stream>>>(W, wtf);
    gat_h_kernel<<<625, 256, 0, stream>>>(X, wtf, Wattn, hb, s_arr, d_arr);
    gat_agg_kernel<<<N_NODES / 4, 256, 0, stream>>>((const uint2*)hb, s_arr, d_arr, edges, out);
}

// Round 10
// 86.376 us; speedup vs baseline: 1.0933x; 1.0522x over previous
//
#include <hip/hip_runtime.h>
#include <math.h>

#define N_NODES 10000
#define DEG1 33          // DEG + self-loop
#define D_EMB 128
#define F_IN 128
#define BATCH 2

typedef short s8v  __attribute__((ext_vector_type(8)));
typedef float f4v  __attribute__((ext_vector_type(4)));

// fp32 -> bf16 round-to-nearest-even (no NaN special-case; inputs are normal)
static __device__ __forceinline__ unsigned short f2bf(float f) {
    unsigned int x = __float_as_uint(f);
    unsigned int r = (x + 0x7fffu + ((x >> 16) & 1u)) >> 16;
    return (unsigned short)r;
}
static __device__ __forceinline__ float rdlane_f(float v, int l) {
    return __uint_as_float((unsigned int)__builtin_amdgcn_readlane((int)__float_as_uint(v), l));
}

// ---------------------------------------------------------------------------
// Kernel 0 (prep): pack W (128x128 fp32) into bf16 B-fragments for
// mfma_f32_16x16x32_bf16:  B[k = s*32 + (l>>4)*8 + j][n = c*16 + (l&15)]
// layout wtf[((c*4+s)*64 + l)*8 + j]  (16B/lane -> coalesced dwordx4 loads).
// ---------------------------------------------------------------------------
__global__ __launch_bounds__(256) void gat_prep_kernel(
    const float* __restrict__ W, unsigned short* __restrict__ wtf)
{
    const int c = blockIdx.x;
    const int t = threadIdx.x;
    __shared__ float xs[128 * 16];   // W[:, c*16 .. c*16+16)
    #pragma unroll
    for (int r = 0; r < 8; ++r) {
        const int k = r * 16 + (t >> 4);
        const int n = t & 15;
        xs[k * 16 + n] = W[k * 128 + c * 16 + n];
    }
    __syncthreads();
    const int s = t >> 6;    // k-step 0..3
    const int l = t & 63;    // lane
    s8v frag;
    #pragma unroll
    for (int j = 0; j < 8; ++j) {
        const int k = s * 32 + (l >> 4) * 8 + j;
        frag[j] = (short)f2bf(xs[k * 16 + (l & 15)]);
    }
    *(s8v*)&wtf[(((size_t)c * 4 + s) * 64 + l) * 8] = frag;
}

// ---------------------------------------------------------------------------
// Kernel 1: h = X @ W via bf16 MFMA (wave = 16 rows x 64 cols, R9 structure).
// Epilogue: per-row absmax (16-lane reduce + LDS combine with the s/d
// partials), then h quantized to INT8 biased-uint8 (u = round(v*127/mx)+128)
// and stored batch-interleaved hb8[(n*2+b)*128 + col] -> the agg gather
// halves to 256B per edge for BOTH batches. Per-node params packed as
// pk4[n] = {d_b0, d_b1, scale_b0, scale_b1} and s2[n] = {s_b0, s_b1}.
// ---------------------------------------------------------------------------
__global__ __launch_bounds__(256) void gat_h_kernel(
    const float* __restrict__ X, const unsigned short* __restrict__ wtf,
    const float* __restrict__ Wattn,
    unsigned char* __restrict__ hb8, float* __restrict__ pk4, float* __restrict__ s2)
{
    __shared__ float lds_sd[2][2][2][16];   // [rowgroup][colhalf][s|d][row]
    __shared__ float lds_mx[2][2][16];      // [rowgroup][colhalf][row] absmax
    const int wave = threadIdx.x >> 6;
    const int lane = threadIdx.x & 63;
    const int quad = lane >> 4;
    const int mrow = lane & 15;
    const int rg   = wave >> 1;              // row-group within block (0,1)
    const int half = wave & 1;               // col half (0,1)
    const int row0 = (blockIdx.x * 2 + rg) * 16;

    f4v acc[4];
    #pragma unroll
    for (int cc = 0; cc < 4; ++cc) acc[cc] = (f4v){0.f, 0.f, 0.f, 0.f};

    const float* xrow = X + (size_t)(row0 + mrow) * F_IN;
    #pragma unroll
    for (int s = 0; s < 4; ++s) {
        const int k0 = s * 32 + quad * 8;
        const float4 xa = *(const float4*)&xrow[k0];
        const float4 xbv = *(const float4*)&xrow[k0 + 4];
        s8v a;
        a[0] = (short)f2bf(xa.x);  a[1] = (short)f2bf(xa.y);
        a[2] = (short)f2bf(xa.z);  a[3] = (short)f2bf(xa.w);
        a[4] = (short)f2bf(xbv.x); a[5] = (short)f2bf(xbv.y);
        a[6] = (short)f2bf(xbv.z); a[7] = (short)f2bf(xbv.w);
        #pragma unroll
        for (int cc = 0; cc < 4; ++cc) {
            const int c = half * 4 + cc;
            const s8v b = *(const s8v*)&wtf[(((size_t)c * 4 + s) * 64 + lane) * 8];
            acc[cc] = __builtin_amdgcn_mfma_f32_16x16x32_bf16(a, b, acc[cc], 0, 0, 0);
        }
    }

    // ---- partial s/d dots + partial row absmax over this wave's 64 cols ----
    float as[4], ad[4];
    #pragma unroll
    for (int cc = 0; cc < 4; ++cc) {
        as[cc] = Wattn[(half * 4 + cc) * 16 + mrow];
        ad[cc] = Wattn[D_EMB + (half * 4 + cc) * 16 + mrow];
    }
    #pragma unroll
    for (int r = 0; r < 4; ++r) {
        float sv = 0.f, dv = 0.f, mx = 0.f;
        #pragma unroll
        for (int cc = 0; cc < 4; ++cc) {
            sv = fmaf(acc[cc][r], as[cc], sv);
            dv = fmaf(acc[cc][r], ad[cc], dv);
            mx = fmaxf(mx, fabsf(acc[cc][r]));
        }
        #pragma unroll
        for (int off = 1; off < 16; off <<= 1) {
            sv += __shfl_xor(sv, off, 16);
            dv += __shfl_xor(dv, off, 16);
            mx = fmaxf(mx, __shfl_xor(mx, off, 16));
        }
        if (mrow == 0) {
            lds_sd[rg][half][0][quad * 4 + r] = sv;
            lds_sd[rg][half][1][quad * 4 + r] = dv;
            lds_mx[rg][half][quad * 4 + r] = mx;
        }
    }
    __syncthreads();

    // ---- quantize + store h (int8 biased, interleaved (n,b)) ----
    const int b = (row0 >= N_NODES) ? 1 : 0;
    #pragma unroll
    for (int r = 0; r < 4; ++r) {
        const int qr = quad * 4 + r;
        const float mx = fmaxf(fmaxf(lds_mx[rg][0][qr], lds_mx[rg][1][qr]), 1e-20f);
        const float inv_s = 127.f / mx;
        const int n = (row0 + qr) - b * N_NODES;
        unsigned char* dst = &hb8[((size_t)n * 2 + b) * D_EMB + half * 64 + mrow];
        #pragma unroll
        for (int cc = 0; cc < 4; ++cc) {
            const float tq = fminf(fmaxf(acc[cc][r] * inv_s, -127.f), 127.f);
            dst[cc * 16] = (unsigned char)(__float2int_rn(tq) + 128);
        }
    }

    // ---- write per-node packed params (one lane per row) ----
    const int t = threadIdx.x;
    if (t < 32) {
        const int rg2 = t >> 4, r = t & 15;
        const int row = (blockIdx.x * 2 + rg2) * 16 + r;
        const int b2 = (row >= N_NODES) ? 1 : 0;
        const int n2 = row - b2 * N_NODES;
        const float s_full = lds_sd[rg2][0][0][r] + lds_sd[rg2][1][0][r];
        const float d_full = lds_sd[rg2][0][1][r] + lds_sd[rg2][1][1][r];
        const float mx = fmaxf(fmaxf(lds_mx[rg2][0][r], lds_mx[rg2][1][r]), 1e-20f);
        s2[(size_t)n2 * 2 + b2] = s_full;
        pk4[(size_t)n2 * 4 + b2] = d_full;            // d for batch b2
        pk4[(size_t)n2 * 4 + 2 + b2] = mx * (1.f / 127.f);  // scale for batch b2
    }
}

// ---------------------------------------------------------------------------
// Kernel 2: edge phase, int8 gather. Wave = node, 4 independent waves per
// 256-thr block, no barriers/LDS. Per edge: ONE dword/lane saddr load covers
// both batches' int8 rows (256B total). Dequant scale folded into per-edge
// weight wS_b = attn_b * scale_b[dst] (attn uses batch-0 denom, ref
// semantics); the int8 bias (-128) collapses to the wave-uniform constant
// C = 128 * sum(wS0 + wS1), subtracted once at the end.
// ---------------------------------------------------------------------------
__global__ __launch_bounds__(256) void gat_agg_kernel(
    const unsigned int* __restrict__ h4,   // int8 rows as dwords
    const float* __restrict__ pk4, const float* __restrict__ s2,
    const int* __restrict__ edges, float* __restrict__ out)
{
    const int i = blockIdx.x * 4 + (threadIdx.x >> 6);   // node
    const int lane = threadIdx.x & 63;

    int dstv = 0; float sc0 = 0.f, wS0 = 0.f, wS1 = 0.f;
    if (lane < DEG1) {
        dstv = edges[((size_t)i * DEG1 + lane) * 2 + 1];
        const float4 pk = *(const float4*)&pk4[(size_t)dstv * 4]; // {d0,d1,sc0,sc1}
        const float s0 = s2[(size_t)i * 2];
        const float s1 = s2[(size_t)i * 2 + 1];
        float x0 = s0 + pk.x;
        float x1 = s1 + pk.y;
        x0 = (x0 >= 0.f) ? x0 : 0.2f * x0;            // leaky_relu(0.2)
        x1 = (x1 >= 0.f) ? x1 : 0.2f * x1;
        sc0 = __expf(fminf(fmaxf(x0, -2.f), 2.f));
        const float sc1 = __expf(fminf(fmaxf(x1, -2.f), 2.f));
        wS0 = sc0 * pk.z;            // attn-numerator * dequant scale
        wS1 = sc1 * pk.w;
    }
    float dsum = sc0;              // denom from batch 0 only (ref semantics)
    #pragma unroll
    for (int off = 1; off < 64; off <<= 1) dsum += __shfl_xor(dsum, off, 64);
    const float inv = 1.f / dsum;
    wS0 *= inv;
    wS1 *= inv;
    float csum = wS0 + wS1;        // for the -128 bias correction
    #pragma unroll
    for (int off = 1; off < 64; off <<= 1) csum += __shfl_xor(csum, off, 64);
    const float C = 128.f * csum;

    // lanes 0..31: batch-0 dims 4*dl..4*dl+3; lanes 32..63: batch-1 same dims
    float4 acc = make_float4(0.f, 0.f, 0.f, 0.f);
    #pragma unroll
    for (int j = 0; j < DEG1; ++j) {
        const int   dd = __builtin_amdgcn_readlane(dstv, j);   // SGPR
        const float w0 = rdlane_f(wS0, j);                     // SGPR
        const float w1 = rdlane_f(wS1, j);                     // SGPR
        const float wgt = (lane < 32) ? w0 : w1;
        const unsigned int u = h4[(size_t)dd * 64 + lane];     // saddr + lane*4
        acc.x = fmaf(wgt, (float)(u & 0xffu), acc.x);
        acc.y = fmaf(wgt, (float)((u >> 8) & 0xffu), acc.y);
        acc.z = fmaf(wgt, (float)((u >> 16) & 0xffu), acc.z);
        acc.w = fmaf(wgt, (float)(u >> 24), acc.w);
    }
    // combine batches (partner lane ^32 holds the other batch, same dims),
    // then subtract the bias correction
    float4 o;
    o.x = acc.x + __shfl_xor(acc.x, 32, 64) - C;
    o.y = acc.y + __shfl_xor(acc.y, 32, 64) - C;
    o.z = acc.z + __shfl_xor(acc.z, 32, 64) - C;
    o.w = acc.w + __shfl_xor(acc.w, 32, 64) - C;

    const int b  = lane >> 5;        // which batch's copy this lane writes
    const int dl = lane & 31;        // dim group
    *(float4*)&out[((size_t)b * N_NODES + i) * D_EMB + dl * 4] = o;
}

extern "C" void kernel_launch(void* const* d_in, const int* in_sizes, int n_in,
                              void* d_out, int out_size, void* d_ws, size_t ws_size,
                              hipStream_t stream) {
    const float* X     = (const float*)d_in[0];   // (2, 10000, 128) fp32
    const float* W     = (const float*)d_in[1];   // (128, 128) fp32
    const float* Wattn = (const float*)d_in[2];   // (256, 1) fp32
    const int*   edges = (const int*)d_in[3];     // (330000, 2) int32
    float* out = (float*)d_out;                   // (2, 10000, 128) fp32

    unsigned short* wtf = (unsigned short*)d_ws;                 // 16384 bf16 = 32KB
    unsigned char*  hb8 = (unsigned char*)(wtf + 16384);         // 2*10000*128 int8 = 2.56MB
    float* pk4 = (float*)(hb8 + (size_t)BATCH * N_NODES * D_EMB); // {d0,d1,s0,s1} per node
    float* s2  = pk4 + (size_t)N_NODES * 4;                       // {s0,s1} per node

    gat_prep_kernel<<<8, 256, 0, stream>>>(W, wtf);
    gat_h_kernel<<<625, 256, 0, stream>>>(X, wtf, Wattn, hb8, pk4, s2);
    gat_agg_kernel<<<N_NODES / 4, 256, 0, stream>>>((const unsigned int*)hb8, pk4, s2, edges, out);
}